// Round 1
// baseline (536.470 us; speedup 1.0000x reference)
//
#include <hip/hip_runtime.h>
#include <math.h>
#include <stdint.h>

#define N_TOK 4096
#define DIM   1024
#define HID   2048
#define NE    8
#define NROWS (N_TOK * 2)   // 8192 (token, k) assignments
#define LDST  72            // transpose-kernel LDS tile stride (shorts)

typedef __attribute__((ext_vector_type(8))) short bf16x8;
typedef __attribute__((ext_vector_type(4))) float f32x4;

__device__ __forceinline__ unsigned short f2bf(float f) {
    union { unsigned int i; float f; } v; v.f = f;
    unsigned int u = v.i;
    return (unsigned short)((u + 0x7FFFu + ((u >> 16) & 1u)) >> 16);
}
__device__ __forceinline__ int clampi(int v, int lo, int hi) {
    return v < lo ? lo : (v > hi ? hi : v);
}
__device__ __forceinline__ void cvt8(const float* p, unsigned short* o) {
    float4 a = *(const float4*)p;
    float4 b = *(const float4*)(p + 4);
    o[0] = f2bf(a.x); o[1] = f2bf(a.y); o[2] = f2bf(a.z); o[3] = f2bf(a.w);
    o[4] = f2bf(b.x); o[5] = f2bf(b.y); o[6] = f2bf(b.z); o[7] = f2bf(b.w);
}
__device__ __forceinline__ float fast_gelu(float v) {
    float c = 0.7978845608028654f * (v + 0.044715f * v * v * v);
    float t = 1.f - 2.f / (1.f + __expf(2.f * c));   // tanh(c)
    return 0.5f * v * (1.f + t);
}
// async global->LDS, 16B per lane; LDS dest = wave-uniform base + lane*16
__device__ __forceinline__ void gload_lds16(const void* g, void* l) {
    __builtin_amdgcn_global_load_lds(
        (const __attribute__((address_space(1))) unsigned int*)g,
        (__attribute__((address_space(3))) unsigned int*)l,
        16, 0, 0);
}

// ---------------- init: zero counts + cursors ----------------
__global__ void init_hdr_kernel(int* __restrict__ hdr) {
    if (threadIdx.x < 32) hdr[threadIdx.x] = 0;
}

// ---------------- gating: one wave per token, pure fp32 ----------------
__global__ __launch_bounds__(256) void gate_kernel(
    const float* __restrict__ x, const float* __restrict__ wg,
    int* __restrict__ counts, unsigned short* __restrict__ top_e, float* __restrict__ top_g)
{
    int wave = threadIdx.x >> 6;
    int lane = threadIdx.x & 63;
    int n = blockIdx.x * 4 + wave;
    if (n >= N_TOK) return;
    float acc[NE];
#pragma unroll
    for (int e = 0; e < NE; e++) acc[e] = 0.f;
    const float* xrow = x + (size_t)n * DIM;
    for (int d = lane; d < DIM; d += 64) {
        float xv = xrow[d];
        float4 wa = *(const float4*)(wg + (size_t)d * NE);
        float4 wb = *(const float4*)(wg + (size_t)d * NE + 4);
        acc[0] += xv * wa.x; acc[1] += xv * wa.y;
        acc[2] += xv * wa.z; acc[3] += xv * wa.w;
        acc[4] += xv * wb.x; acc[5] += xv * wb.y;
        acc[6] += xv * wb.z; acc[7] += xv * wb.w;
    }
#pragma unroll
    for (int e = 0; e < NE; e++) {
        float v = acc[e];
#pragma unroll
        for (int off = 32; off > 0; off >>= 1) v += __shfl_xor(v, off, 64);
        acc[e] = v;
    }
    if (lane == 0) {
        int e0 = 0; float v0 = acc[0];
#pragma unroll
        for (int e = 1; e < NE; e++) if (acc[e] > v0) { v0 = acc[e]; e0 = e; }
        int e1 = (e0 == 0) ? 1 : 0; float v1 = acc[e1];
#pragma unroll
        for (int e = 0; e < NE; e++) if (e != e0 && acc[e] > v1) { v1 = acc[e]; e1 = e; }
        float s = expf(v1 - v0);
        float g0 = 1.f / (1.f + s);
        float g1 = s / (1.f + s);
        atomicAdd(&counts[e0], 1);
        atomicAdd(&counts[e1], 1);
        top_e[n] = (unsigned short)(e0 | (e1 << 8));
        top_g[2 * n + 0] = g0;
        top_g[2 * n + 1] = g1;
    }
}

// ---------------- scatter: per-expert row lists; row_tok = (n<<1)|k ----------------
__global__ __launch_bounds__(256) void scatter_kernel(
    const int* __restrict__ counts, int* __restrict__ cursors,
    const unsigned short* __restrict__ top_e, const float* __restrict__ top_g,
    int* __restrict__ row_tok, float* __restrict__ row_gate)
{
    int n = blockIdx.x * 256 + threadIdx.x;
    if (n >= N_TOK) return;
    int off[NE]; int a = 0;
#pragma unroll
    for (int e = 0; e < NE; e++) { off[e] = a; a += clampi(counts[e], 0, NROWS); }
    int te = top_e[n];
#pragma unroll
    for (int k = 0; k < 2; k++) {
        int e = clampi((k == 0) ? (te & 0xFF) : ((te >> 8) & 0xFF), 0, NE - 1);
        int pos = atomicAdd(&cursors[e], 1);
        int r = clampi(off[e] + pos, 0, NROWS - 1);
        row_tok[r]  = (n << 1) | k;
        row_gate[r] = top_g[2 * n + k];
    }
}

// ---------------- pack x: fp32 [N][D] -> bf16 [N][D] (one-time cast) ----------------
__global__ __launch_bounds__(256) void pack_x_kernel(
    const float* __restrict__ x, unsigned short* __restrict__ xb)
{
    size_t i = (size_t)(blockIdx.x * 256 + threadIdx.x) * 8;
    unsigned short o[8];
    cvt8(x + i, o);
    *(uint4*)(xb + i) = *(uint4*)o;
}

// ---------------- transpose+cast: in[e][K][N] fp32 -> out[e][N][K] bf16 ----------------
__global__ __launch_bounds__(256) void transpose_kernel(
    const float* __restrict__ in, unsigned short* __restrict__ outp, int K, int N)
{
    int e  = blockIdx.z;
    int kb = blockIdx.x;
    int nb = blockIdx.y;
    __shared__ __align__(16) unsigned short tile[64 * LDST];
    int t = threadIdx.x;

    int r = t >> 2, cq = t & 3;
    const float* sp = in + ((size_t)e * K + kb * 64 + r) * N + nb * 64 + cq * 16;
    unsigned short v[16];
    cvt8(sp, v);
    cvt8(sp + 8, v + 8);
    *(uint4*)(&tile[r * LDST + cq * 16 + 0]) = *(uint4*)(v + 0);
    *(uint4*)(&tile[r * LDST + cq * 16 + 8]) = *(uint4*)(v + 8);
    __syncthreads();

    int c = t >> 2, kq = t & 3;
    unsigned short o[16];
#pragma unroll
    for (int i = 0; i < 16; i++) o[i] = tile[(kq * 16 + i) * LDST + c];
    unsigned short* dp = outp + ((size_t)e * N + nb * 64 + c) * K + kb * 64 + kq * 16;
    *(uint4*)(dp + 0) = *(uint4*)(o + 0);
    *(uint4*)(dp + 8) = *(uint4*)(o + 8);
}

// ---------------- FFN1: 128x128 tile, BK=64, global_load_lds staging (m97 structure) ----------------
__global__ __launch_bounds__(256) void ffn1_fast2(
    const unsigned short* __restrict__ xb,    // [N][D] bf16
    const unsigned short* __restrict__ w1t,   // [e][H][D] bf16
    const float* __restrict__ b1,
    const int* __restrict__ counts,
    const int* __restrict__ row_tok,
    unsigned short* __restrict__ h)
{
    int id = blockIdx.x;
    int nb = id % (HID / 128);
    int rest = id / (HID / 128);
    int e  = rest % NE;
    int mb = rest / NE;

    int off = 0;
#pragma unroll
    for (int i = 0; i < NE; i++) { int c = clampi(counts[i], 0, NROWS); if (i < e) off += c; }
    int cnt  = clampi(counts[e], 0, NROWS);
    int row0 = mb * 128;
    if (row0 >= cnt) return;
    int nvalid = clampi(cnt - row0, 1, 128);

    // linear [128][64] bf16 tiles — REQUIRED layout for global_load_lds (no padding)
    __shared__ __align__(16) unsigned short lA[128 * 64];
    __shared__ __align__(16) unsigned short lB[128 * 64];
    __shared__ int ltok[128];

    int t = threadIdx.x;
    if (t < 128) {
        int rl = clampi(t, 0, nvalid - 1);
        int idx = clampi(off + row0 + rl, 0, NROWS - 1);
        ltok[t] = clampi(row_tok[idx] >> 1, 0, N_TOK - 1);   // decode token
    }
    __syncthreads();

    const int n0 = nb * 128;
    int w = t >> 6;
    // per-round per-lane GLOBAL sources (gather via ltok is free: global addr is per-lane)
    const unsigned short* ga[4];
    const unsigned short* gb[4];
    unsigned short* la[4];
    unsigned short* lb[4];
#pragma unroll
    for (int i = 0; i < 4; i++) {
        int idx = i * 256 + t;              // 0..1023 -> (row, 16B-chunk)
        int row = idx >> 3, cc = idx & 7;
        ga[i] = xb + (size_t)ltok[row] * DIM + cc * 8;
        gb[i] = w1t + ((size_t)e * HID + n0 + row) * DIM + cc * 8;
        la[i] = lA + i * 2048 + w * 512;    // wave-uniform LDS dest base (shorts)
        lb[i] = lB + i * 2048 + w * 512;
    }

    int lane = t & 63, quad = lane >> 4, ln = lane & 15;
    int wr = w >> 1, wc = w & 1;
    f32x4 acc[4][4];
#pragma unroll
    for (int i = 0; i < 4; i++)
#pragma unroll
        for (int j = 0; j < 4; j++) acc[i][j] = (f32x4){0.f, 0.f, 0.f, 0.f};

    for (int kt = 0; kt < DIM / 64; kt++) {
        int k0 = kt * 64;
#pragma unroll
        for (int i = 0; i < 4; i++) {
            gload_lds16(ga[i] + k0, la[i]);
            gload_lds16(gb[i] + k0, lb[i]);
        }
        __syncthreads();   // compiler drains vmcnt(0) before barrier
#pragma unroll
        for (int kk = 0; kk < 2; kk++) {
            bf16x8 af[4], bf[4];
#pragma unroll
            for (int s = 0; s < 4; s++)
                af[s] = *(const bf16x8*)(&lA[(wr * 64 + s * 16 + ln) * 64 + kk * 32 + quad * 8]);
#pragma unroll
            for (int s = 0; s < 4; s++)
                bf[s] = *(const bf16x8*)(&lB[(wc * 64 + s * 16 + ln) * 64 + kk * 32 + quad * 8]);
#pragma unroll
            for (int i = 0; i < 4; i++)
#pragma unroll
                for (int j = 0; j < 4; j++)
                    acc[i][j] = __builtin_amdgcn_mfma_f32_16x16x32_bf16(af[i], bf[j], acc[i][j], 0, 0, 0);
        }
        __syncthreads();
    }

    int gr0 = off + row0;
#pragma unroll
    for (int j = 0; j < 4; j++) {
        int col = n0 + wc * 64 + j * 16 + ln;
        float bias = b1[e * HID + col];
#pragma unroll
        for (int i = 0; i < 4; i++) {
#pragma unroll
            for (int r = 0; r < 4; r++) {
                int m = wr * 64 + i * 16 + quad * 4 + r;
                if (m < nvalid)
                    h[(size_t)(gr0 + m) * HID + col] = f2bf(fast_gelu(acc[i][j][r] + bias));
            }
        }
    }
}

// ---------------- FFN2: 128x128 tile, global_load_lds staging, slot-split epilogue ----------------
__global__ __launch_bounds__(256) void ffn2_fast4(
    const unsigned short* __restrict__ h,
    const unsigned short* __restrict__ w2t,   // [e][D][H] bf16
    const float* __restrict__ b2,
    const int* __restrict__ counts,
    const int* __restrict__ row_tok,
    const float* __restrict__ row_gate,
    float* __restrict__ out,                  // k=0 slot
    float* __restrict__ ybuf1)                // k=1 slot
{
    int id = blockIdx.x;
    int nb = id % (DIM / 128);
    int rest = id / (DIM / 128);
    int e  = rest % NE;
    int mb = rest / NE;

    int off = 0;
#pragma unroll
    for (int i = 0; i < NE; i++) { int c = clampi(counts[i], 0, NROWS); if (i < e) off += c; }
    int cnt  = clampi(counts[e], 0, NROWS);
    int row0 = mb * 128;
    if (row0 >= cnt) return;
    int nvalid = clampi(cnt - row0, 1, 128);

    __shared__ __align__(16) unsigned short lA[128 * 64];
    __shared__ __align__(16) unsigned short lB[128 * 64];
    __shared__ int   ltok2[128];              // (n<<1)|k
    __shared__ float lgate[128];

    int t = threadIdx.x;
    if (t < 128) {
        int rl = clampi(t, 0, nvalid - 1);
        int idx = clampi(off + row0 + rl, 0, NROWS - 1);
        ltok2[t] = clampi(row_tok[idx], 0, 2 * N_TOK - 1);
        lgate[t] = row_gate[idx];
    }
    __syncthreads();

    const int n0 = nb * 128;
    int w = t >> 6;
    const unsigned short* ga[4];
    const unsigned short* gb[4];
    unsigned short* la[4];
    unsigned short* lb[4];
#pragma unroll
    for (int i = 0; i < 4; i++) {
        int idx = i * 256 + t;
        int row = idx >> 3, cc = idx & 7;
        int arow = clampi(off + row0 + row, 0, NROWS - 1);
        ga[i] = h + (size_t)arow * HID + cc * 8;
        gb[i] = w2t + ((size_t)e * DIM + n0 + row) * HID + cc * 8;
        la[i] = lA + i * 2048 + w * 512;
        lb[i] = lB + i * 2048 + w * 512;
    }

    int lane = t & 63, quad = lane >> 4, ln = lane & 15;
    int wr = w >> 1, wc = w & 1;
    f32x4 acc[4][4];
#pragma unroll
    for (int i = 0; i < 4; i++)
#pragma unroll
        for (int j = 0; j < 4; j++) acc[i][j] = (f32x4){0.f, 0.f, 0.f, 0.f};

    for (int kt = 0; kt < HID / 64; kt++) {
        int k0 = kt * 64;
#pragma unroll
        for (int i = 0; i < 4; i++) {
            gload_lds16(ga[i] + k0, la[i]);
            gload_lds16(gb[i] + k0, lb[i]);
        }
        __syncthreads();
#pragma unroll
        for (int kk = 0; kk < 2; kk++) {
            bf16x8 af[4], bf[4];
#pragma unroll
            for (int s = 0; s < 4; s++)
                af[s] = *(const bf16x8*)(&lA[(wr * 64 + s * 16 + ln) * 64 + kk * 32 + quad * 8]);
#pragma unroll
            for (int s = 0; s < 4; s++)
                bf[s] = *(const bf16x8*)(&lB[(wc * 64 + s * 16 + ln) * 64 + kk * 32 + quad * 8]);
#pragma unroll
            for (int i = 0; i < 4; i++)
#pragma unroll
                for (int j = 0; j < 4; j++)
                    acc[i][j] = __builtin_amdgcn_mfma_f32_16x16x32_bf16(af[i], bf[j], acc[i][j], 0, 0, 0);
        }
        __syncthreads();
    }

#pragma unroll
    for (int j = 0; j < 4; j++) {
        int col = n0 + wc * 64 + j * 16 + ln;
        float bias = b2[e * DIM + col];
#pragma unroll
        for (int i = 0; i < 4; i++) {
#pragma unroll
            for (int r = 0; r < 4; r++) {
                int m = wr * 64 + i * 16 + quad * 4 + r;
                if (m < nvalid) {
                    int rt  = ltok2[m];
                    int tok = rt >> 1;
                    float vv = (acc[i][j][r] + bias) * lgate[m];
                    float* dst = (rt & 1) ? ybuf1 : out;    // exactly one writer per (tok,col,k)
                    dst[(size_t)tok * DIM + col] = vv;
                }
            }
        }
    }
}

// ---------------- combine: out += ybuf1 ----------------
__global__ __launch_bounds__(256) void combine_kernel(
    float4* __restrict__ out4, const float4* __restrict__ y4)
{
    int i = blockIdx.x * 256 + threadIdx.x;   // 1M float4
    float4 a = out4[i];
    float4 b = y4[i];
    out4[i] = make_float4(a.x + b.x, a.y + b.y, a.z + b.z, a.w + b.w);
}

__global__ __launch_bounds__(256) void zero_out_kernel(float* __restrict__ out) {
    int i = blockIdx.x * 256 + threadIdx.x;
    out[i] = 0.f;
}

// ================= host =================
extern "C" void kernel_launch(void* const* d_in, const int* in_sizes, int n_in,
                              void* d_out, int out_size, void* d_ws, size_t ws_size,
                              hipStream_t stream) {
    const float* x  = (const float*)d_in[0];
    const float* wg = (const float*)d_in[1];
    const float* w1 = (const float*)d_in[2];
    const float* b1 = (const float*)d_in[3];
    const float* w2 = (const float*)d_in[4];
    const float* b2 = (const float*)d_in[5];
    float* out = (float*)d_out;

    // Header (first 128 KB):
    //   [0,64)        counts (8 int)
    //   [64,128)      cursors (8 int)
    //   [256,8448)    top_e  ushort[4096]
    //   [8448,41216)  top_g  f32[8192]
    //   [41216,73984) row_tok int[8192]   ((n<<1)|k)
    //   [73984,106752) row_gate f32[8192]
    // Data: wt 32M | hbuf 32M | ybuf1 16M  => total 84,017,152 B (unchanged)
    // xb (bf16 x, 8M) ALIASES the first half of ybuf1: pack_x -> ffn1 reads it,
    // then ffn2 overwrites ybuf1 (stream-ordered, safe).
    char* ws = (char*)d_ws;
    int*            counts   = (int*)(ws + 0);
    int*            cursors  = (int*)(ws + 64);
    unsigned short* top_e    = (unsigned short*)(ws + 256);
    float*          top_g    = (float*)(ws + 8448);
    int*            row_tok  = (int*)(ws + 41216);
    float*          row_gate = (float*)(ws + 73984);

    const size_t WT_OFF    = (size_t)1 << 17;
    const size_t HBUF_OFF  = WT_OFF + (size_t)NE * DIM * HID * 2;      // +32M
    const size_t YBUF_OFF  = HBUF_OFF + (size_t)NROWS * HID * 2;       // +32M
    const size_t NEEDED    = YBUF_OFF + (size_t)N_TOK * DIM * 4;       // +16M = 84,017,152

    if (ws_size < NEEDED) {
        zero_out_kernel<<<dim3(N_TOK * DIM / 256), dim3(256), 0, stream>>>(out);
        return;
    }

    unsigned short* wt    = (unsigned short*)(ws + WT_OFF);
    unsigned short* hbuf  = (unsigned short*)(ws + HBUF_OFF);
    float*          ybuf1 = (float*)(ws + YBUF_OFF);
    unsigned short* xb    = (unsigned short*)(ws + YBUF_OFF);          // alias (see above)

    init_hdr_kernel<<<dim3(1), dim3(64), 0, stream>>>((int*)ws);
    gate_kernel<<<dim3(N_TOK / 4), dim3(256), 0, stream>>>(x, wg, counts, top_e, top_g);
    scatter_kernel<<<dim3(N_TOK / 256), dim3(256), 0, stream>>>(counts, cursors, top_e, top_g, row_tok, row_gate);
    pack_x_kernel<<<dim3(N_TOK * DIM / (256 * 8)), dim3(256), 0, stream>>>(x, xb);
    // w1 [e][D][H] -> w1T [e][H][D]
    transpose_kernel<<<dim3(DIM / 64, HID / 64, NE), dim3(256), 0, stream>>>(w1, wt, DIM, HID);
    ffn1_fast2<<<dim3(64 * NE * (HID / 128)), dim3(256), 0, stream>>>(xb, wt, b1, counts, row_tok, hbuf);
    // w2 [e][H][D] -> w2T [e][D][H]
    transpose_kernel<<<dim3(HID / 64, DIM / 64, NE), dim3(256), 0, stream>>>(w2, wt, HID, DIM);
    ffn2_fast4<<<dim3(64 * NE * (DIM / 128)), dim3(256), 0, stream>>>(hbuf, wt, b2, counts, row_tok, row_gate, out, ybuf1);
    combine_kernel<<<dim3(N_TOK * DIM / 1024), dim3(256), 0, stream>>>((float4*)out, (const float4*)ybuf1);
}

// Round 2
// 514.863 us; speedup vs baseline: 1.0420x; 1.0420x over previous
//
#include <hip/hip_runtime.h>
#include <math.h>
#include <stdint.h>

#define N_TOK 4096
#define DIM   1024
#define HID   2048
#define NE    8
#define NROWS (N_TOK * 2)   // 8192 (token, k) assignments
#define LDST  72            // transpose-kernel LDS tile stride (shorts)
#define OBST  144           // epilogue bounce stride (shorts): 288B rows, 16B-aligned, conflict-spread

typedef __attribute__((ext_vector_type(8))) short bf16x8;
typedef __attribute__((ext_vector_type(4))) float f32x4;

__device__ __forceinline__ unsigned short f2bf(float f) {
    union { unsigned int i; float f; } v; v.f = f;
    unsigned int u = v.i;
    return (unsigned short)((u + 0x7FFFu + ((u >> 16) & 1u)) >> 16);
}
__device__ __forceinline__ int clampi(int v, int lo, int hi) {
    return v < lo ? lo : (v > hi ? hi : v);
}
__device__ __forceinline__ void cvt8(const float* p, unsigned short* o) {
    float4 a = *(const float4*)p;
    float4 b = *(const float4*)(p + 4);
    o[0] = f2bf(a.x); o[1] = f2bf(a.y); o[2] = f2bf(a.z); o[3] = f2bf(a.w);
    o[4] = f2bf(b.x); o[5] = f2bf(b.y); o[6] = f2bf(b.z); o[7] = f2bf(b.w);
}
__device__ __forceinline__ float fast_gelu(float v) {
    float c = 0.7978845608028654f * (v + 0.044715f * v * v * v);
    float t = 1.f - 2.f / (1.f + __expf(2.f * c));   // tanh(c)
    return 0.5f * v * (1.f + t);
}
// async global->LDS, 16B per lane; LDS dest = wave-uniform base + lane*16
__device__ __forceinline__ void gload_lds16(const void* g, void* l) {
    __builtin_amdgcn_global_load_lds(
        (const __attribute__((address_space(1))) unsigned int*)g,
        (__attribute__((address_space(3))) unsigned int*)l,
        16, 0, 0);
}

// ---------------- init: zero counts + cursors ----------------
__global__ void init_hdr_kernel(int* __restrict__ hdr) {
    if (threadIdx.x < 32) hdr[threadIdx.x] = 0;
}

// ---------------- gating: one wave per token, pure fp32 ----------------
__global__ __launch_bounds__(256) void gate_kernel(
    const float* __restrict__ x, const float* __restrict__ wg,
    int* __restrict__ counts, unsigned short* __restrict__ top_e, float* __restrict__ top_g)
{
    int wave = threadIdx.x >> 6;
    int lane = threadIdx.x & 63;
    int n = blockIdx.x * 4 + wave;
    if (n >= N_TOK) return;
    float acc[NE];
#pragma unroll
    for (int e = 0; e < NE; e++) acc[e] = 0.f;
    const float* xrow = x + (size_t)n * DIM;
    for (int d = lane; d < DIM; d += 64) {
        float xv = xrow[d];
        float4 wa = *(const float4*)(wg + (size_t)d * NE);
        float4 wb = *(const float4*)(wg + (size_t)d * NE + 4);
        acc[0] += xv * wa.x; acc[1] += xv * wa.y;
        acc[2] += xv * wa.z; acc[3] += xv * wa.w;
        acc[4] += xv * wb.x; acc[5] += xv * wb.y;
        acc[6] += xv * wb.z; acc[7] += xv * wb.w;
    }
#pragma unroll
    for (int e = 0; e < NE; e++) {
        float v = acc[e];
#pragma unroll
        for (int off = 32; off > 0; off >>= 1) v += __shfl_xor(v, off, 64);
        acc[e] = v;
    }
    if (lane == 0) {
        int e0 = 0; float v0 = acc[0];
#pragma unroll
        for (int e = 1; e < NE; e++) if (acc[e] > v0) { v0 = acc[e]; e0 = e; }
        int e1 = (e0 == 0) ? 1 : 0; float v1 = acc[e1];
#pragma unroll
        for (int e = 0; e < NE; e++) if (e != e0 && acc[e] > v1) { v1 = acc[e]; e1 = e; }
        float s = expf(v1 - v0);
        float g0 = 1.f / (1.f + s);
        float g1 = s / (1.f + s);
        atomicAdd(&counts[e0], 1);
        atomicAdd(&counts[e1], 1);
        top_e[n] = (unsigned short)(e0 | (e1 << 8));
        top_g[2 * n + 0] = g0;
        top_g[2 * n + 1] = g1;
    }
}

// ---------------- scatter: per-expert row lists; row_tok = (n<<1)|k ----------------
__global__ __launch_bounds__(256) void scatter_kernel(
    const int* __restrict__ counts, int* __restrict__ cursors,
    const unsigned short* __restrict__ top_e, const float* __restrict__ top_g,
    int* __restrict__ row_tok, float* __restrict__ row_gate)
{
    int n = blockIdx.x * 256 + threadIdx.x;
    if (n >= N_TOK) return;
    int off[NE]; int a = 0;
#pragma unroll
    for (int e = 0; e < NE; e++) { off[e] = a; a += clampi(counts[e], 0, NROWS); }
    int te = top_e[n];
#pragma unroll
    for (int k = 0; k < 2; k++) {
        int e = clampi((k == 0) ? (te & 0xFF) : ((te >> 8) & 0xFF), 0, NE - 1);
        int pos = atomicAdd(&cursors[e], 1);
        int r = clampi(off[e] + pos, 0, NROWS - 1);
        row_tok[r]  = (n << 1) | k;
        row_gate[r] = top_g[2 * n + k];
    }
}

// ---------------- pack x: fp32 [N][D] -> bf16 [N][D] (one-time cast) ----------------
__global__ __launch_bounds__(256) void pack_x_kernel(
    const float* __restrict__ x, unsigned short* __restrict__ xb)
{
    size_t i = (size_t)(blockIdx.x * 256 + threadIdx.x) * 8;
    unsigned short o[8];
    cvt8(x + i, o);
    *(uint4*)(xb + i) = *(uint4*)o;
}

// ---------------- transpose+cast: in[e][K][N] fp32 -> out[e][N][K] bf16 ----------------
__global__ __launch_bounds__(256) void transpose_kernel(
    const float* __restrict__ in, unsigned short* __restrict__ outp, int K, int N)
{
    int e  = blockIdx.z;
    int kb = blockIdx.x;
    int nb = blockIdx.y;
    __shared__ __align__(16) unsigned short tile[64 * LDST];
    int t = threadIdx.x;

    int r = t >> 2, cq = t & 3;
    const float* sp = in + ((size_t)e * K + kb * 64 + r) * N + nb * 64 + cq * 16;
    unsigned short v[16];
    cvt8(sp, v);
    cvt8(sp + 8, v + 8);
    *(uint4*)(&tile[r * LDST + cq * 16 + 0]) = *(uint4*)(v + 0);
    *(uint4*)(&tile[r * LDST + cq * 16 + 8]) = *(uint4*)(v + 8);
    __syncthreads();

    int c = t >> 2, kq = t & 3;
    unsigned short o[16];
#pragma unroll
    for (int i = 0; i < 16; i++) o[i] = tile[(kq * 16 + i) * LDST + c];
    unsigned short* dp = outp + ((size_t)e * N + nb * 64 + c) * K + kb * 64 + kq * 16;
    *(uint4*)(dp + 0) = *(uint4*)(o + 0);
    *(uint4*)(dp + 8) = *(uint4*)(o + 8);
}

// ---------------- FFN1: 128x128 tile, BK=64, DOUBLE-BUFFERED pipelined staging ----------------
// T3-minimum 2-phase: STAGE(next) issued BEFORE compute(cur); one vmcnt(0)+barrier per K-step.
__global__ __launch_bounds__(256) void ffn1_fast3(
    const unsigned short* __restrict__ xb,    // [N][D] bf16
    const unsigned short* __restrict__ w1t,   // [e][H][D] bf16
    const float* __restrict__ b1,
    const int* __restrict__ counts,
    const int* __restrict__ row_tok,
    unsigned short* __restrict__ h)
{
    int id = blockIdx.x;
    int nb = id % (HID / 128);
    int rest = id / (HID / 128);
    int e  = rest % NE;
    int mb = rest / NE;

    int off = 0;
#pragma unroll
    for (int i = 0; i < NE; i++) { int c = clampi(counts[i], 0, NROWS); if (i < e) off += c; }
    int cnt  = clampi(counts[e], 0, NROWS);
    int row0 = mb * 128;
    if (row0 >= cnt) return;
    int nvalid = clampi(cnt - row0, 1, 128);

    // [buf][A|B][128][64] bf16, linear (required by global_load_lds). 64 KB total.
    // Epilogue reuses the same region as a [128][OBST] bounce tile.
    __shared__ __align__(16) unsigned short lds[4 * 8192];
    __shared__ int ltok[128];

    int t = threadIdx.x;
    if (t < 128) {
        int rl = clampi(t, 0, nvalid - 1);
        int idx = clampi(off + row0 + rl, 0, NROWS - 1);
        ltok[t] = clampi(row_tok[idx] >> 1, 0, N_TOK - 1);   // decode token
    }
    __syncthreads();

    const int n0 = nb * 128;
    int w = t >> 6;
    const unsigned short* ga[4];
    const unsigned short* gb[4];
    int lofs[4];
#pragma unroll
    for (int i = 0; i < 4; i++) {
        int idx = i * 256 + t;              // 0..1023 -> (row, 16B-chunk)
        int row = idx >> 3, cc = idx & 7;
        ga[i] = xb + (size_t)ltok[row] * DIM + cc * 8;
        gb[i] = w1t + ((size_t)e * HID + n0 + row) * DIM + cc * 8;
        lofs[i] = i * 2048 + w * 512;       // wave-uniform LDS dest (shorts, within a buffer)
    }

    int lane = t & 63, quad = lane >> 4, ln = lane & 15;
    int wr = w >> 1, wc = w & 1;
    f32x4 acc[4][4];
#pragma unroll
    for (int i = 0; i < 4; i++)
#pragma unroll
        for (int j = 0; j < 4; j++) acc[i][j] = (f32x4){0.f, 0.f, 0.f, 0.f};

    // prologue: stage tile 0 into buffer 0
#pragma unroll
    for (int i = 0; i < 4; i++) {
        gload_lds16(ga[i], lds + lofs[i]);
        gload_lds16(gb[i], lds + 8192 + lofs[i]);
    }
    __syncthreads();                         // drains vmcnt(0)

    int cur = 0;
    for (int kt = 0; kt < DIM / 64; kt++) {
        int nxt = cur ^ 1;
        if (kt + 1 < DIM / 64) {             // issue NEXT tile's loads before computing current
            int k0 = (kt + 1) * 64;
            unsigned short* dA = lds + nxt * 16384;
            unsigned short* dB = dA + 8192;
#pragma unroll
            for (int i = 0; i < 4; i++) {
                gload_lds16(ga[i] + k0, dA + lofs[i]);
                gload_lds16(gb[i] + k0, dB + lofs[i]);
            }
        }
        const unsigned short* sA = lds + cur * 16384;
        const unsigned short* sB = sA + 8192;
#pragma unroll
        for (int kk = 0; kk < 2; kk++) {
            bf16x8 af[4], bf[4];
#pragma unroll
            for (int s = 0; s < 4; s++)
                af[s] = *(const bf16x8*)(&sA[(wr * 64 + s * 16 + ln) * 64 + kk * 32 + quad * 8]);
#pragma unroll
            for (int s = 0; s < 4; s++)
                bf[s] = *(const bf16x8*)(&sB[(wc * 64 + s * 16 + ln) * 64 + kk * 32 + quad * 8]);
#pragma unroll
            for (int i = 0; i < 4; i++)
#pragma unroll
                for (int j = 0; j < 4; j++)
                    acc[i][j] = __builtin_amdgcn_mfma_f32_16x16x32_bf16(af[i], bf[j], acc[i][j], 0, 0, 0);
        }
        __syncthreads();                     // drains vmcnt(0)+lgkmcnt(0): next buffer ready, cur reads done
        cur = nxt;
    }

    // epilogue: bounce tile through LDS, store coalesced 256B rows
    unsigned short* ob = lds;                // [128][OBST]
#pragma unroll
    for (int j = 0; j < 4; j++) {
        int colL = wc * 64 + j * 16 + ln;
        float bias = b1[e * HID + n0 + colL];
#pragma unroll
        for (int i = 0; i < 4; i++) {
#pragma unroll
            for (int r = 0; r < 4; r++) {
                int m = wr * 64 + i * 16 + quad * 4 + r;
                ob[m * OBST + colL] = f2bf(fast_gelu(acc[i][j][r] + bias));
            }
        }
    }
    __syncthreads();
    int gr0 = off + row0;
#pragma unroll
    for (int it = 0; it < 8; it++) {
        int idx = it * 256 + t;              // 0..2047 -> (row, 16B-chunk)
        int m = idx >> 4, ch = idx & 15;
        if (m < nvalid)
            *(uint4*)(h + (size_t)(gr0 + m) * HID + n0 + ch * 8) = *(const uint4*)(ob + m * OBST + ch * 8);
    }
}

// ---------------- FFN2: 128x128 tile, DOUBLE-BUFFERED pipelined staging, slot-split epilogue ----------------
__global__ __launch_bounds__(256) void ffn2_fast5(
    const unsigned short* __restrict__ h,
    const unsigned short* __restrict__ w2t,   // [e][D][H] bf16
    const float* __restrict__ b2,
    const int* __restrict__ counts,
    const int* __restrict__ row_tok,
    const float* __restrict__ row_gate,
    float* __restrict__ out,                  // k=0 slot
    float* __restrict__ ybuf1)                // k=1 slot
{
    int id = blockIdx.x;
    int nb = id % (DIM / 128);
    int rest = id / (DIM / 128);
    int e  = rest % NE;
    int mb = rest / NE;

    int off = 0;
#pragma unroll
    for (int i = 0; i < NE; i++) { int c = clampi(counts[i], 0, NROWS); if (i < e) off += c; }
    int cnt  = clampi(counts[e], 0, NROWS);
    int row0 = mb * 128;
    if (row0 >= cnt) return;
    int nvalid = clampi(cnt - row0, 1, 128);

    __shared__ __align__(16) unsigned short lds[4 * 8192];   // [buf][A|B][128][64]
    __shared__ int   ltok2[128];              // (n<<1)|k
    __shared__ float lgate[128];

    int t = threadIdx.x;
    if (t < 128) {
        int rl = clampi(t, 0, nvalid - 1);
        int idx = clampi(off + row0 + rl, 0, NROWS - 1);
        ltok2[t] = clampi(row_tok[idx], 0, 2 * N_TOK - 1);
        lgate[t] = row_gate[idx];
    }
    __syncthreads();

    const int n0 = nb * 128;
    int w = t >> 6;
    const unsigned short* ga[4];
    const unsigned short* gb[4];
    int lofs[4];
#pragma unroll
    for (int i = 0; i < 4; i++) {
        int idx = i * 256 + t;
        int row = idx >> 3, cc = idx & 7;
        int arow = clampi(off + row0 + row, 0, NROWS - 1);
        ga[i] = h + (size_t)arow * HID + cc * 8;
        gb[i] = w2t + ((size_t)e * DIM + n0 + row) * HID + cc * 8;
        lofs[i] = i * 2048 + w * 512;
    }

    int lane = t & 63, quad = lane >> 4, ln = lane & 15;
    int wr = w >> 1, wc = w & 1;
    f32x4 acc[4][4];
#pragma unroll
    for (int i = 0; i < 4; i++)
#pragma unroll
        for (int j = 0; j < 4; j++) acc[i][j] = (f32x4){0.f, 0.f, 0.f, 0.f};

    // prologue
#pragma unroll
    for (int i = 0; i < 4; i++) {
        gload_lds16(ga[i], lds + lofs[i]);
        gload_lds16(gb[i], lds + 8192 + lofs[i]);
    }
    __syncthreads();

    int cur = 0;
    for (int kt = 0; kt < HID / 64; kt++) {
        int nxt = cur ^ 1;
        if (kt + 1 < HID / 64) {
            int k0 = (kt + 1) * 64;
            unsigned short* dA = lds + nxt * 16384;
            unsigned short* dB = dA + 8192;
#pragma unroll
            for (int i = 0; i < 4; i++) {
                gload_lds16(ga[i] + k0, dA + lofs[i]);
                gload_lds16(gb[i] + k0, dB + lofs[i]);
            }
        }
        const unsigned short* sA = lds + cur * 16384;
        const unsigned short* sB = sA + 8192;
#pragma unroll
        for (int kk = 0; kk < 2; kk++) {
            bf16x8 af[4], bf[4];
#pragma unroll
            for (int s = 0; s < 4; s++)
                af[s] = *(const bf16x8*)(&sA[(wr * 64 + s * 16 + ln) * 64 + kk * 32 + quad * 8]);
#pragma unroll
            for (int s = 0; s < 4; s++)
                bf[s] = *(const bf16x8*)(&sB[(wc * 64 + s * 16 + ln) * 64 + kk * 32 + quad * 8]);
#pragma unroll
            for (int i = 0; i < 4; i++)
#pragma unroll
                for (int j = 0; j < 4; j++)
                    acc[i][j] = __builtin_amdgcn_mfma_f32_16x16x32_bf16(af[i], bf[j], acc[i][j], 0, 0, 0);
        }
        __syncthreads();
        cur = nxt;
    }

#pragma unroll
    for (int j = 0; j < 4; j++) {
        int col = n0 + wc * 64 + j * 16 + ln;
        float bias = b2[e * DIM + col];
#pragma unroll
        for (int i = 0; i < 4; i++) {
#pragma unroll
            for (int r = 0; r < 4; r++) {
                int m = wr * 64 + i * 16 + quad * 4 + r;
                if (m < nvalid) {
                    int rt  = ltok2[m];
                    int tok = rt >> 1;
                    float vv = (acc[i][j][r] + bias) * lgate[m];
                    float* dst = (rt & 1) ? ybuf1 : out;    // exactly one writer per (tok,col,k)
                    dst[(size_t)tok * DIM + col] = vv;
                }
            }
        }
    }
}

// ---------------- combine: out += ybuf1 ----------------
__global__ __launch_bounds__(256) void combine_kernel(
    float4* __restrict__ out4, const float4* __restrict__ y4)
{
    int i = blockIdx.x * 256 + threadIdx.x;   // 1M float4
    float4 a = out4[i];
    float4 b = y4[i];
    out4[i] = make_float4(a.x + b.x, a.y + b.y, a.z + b.z, a.w + b.w);
}

__global__ __launch_bounds__(256) void zero_out_kernel(float* __restrict__ out) {
    int i = blockIdx.x * 256 + threadIdx.x;
    out[i] = 0.f;
}

// ================= host =================
extern "C" void kernel_launch(void* const* d_in, const int* in_sizes, int n_in,
                              void* d_out, int out_size, void* d_ws, size_t ws_size,
                              hipStream_t stream) {
    const float* x  = (const float*)d_in[0];
    const float* wg = (const float*)d_in[1];
    const float* w1 = (const float*)d_in[2];
    const float* b1 = (const float*)d_in[3];
    const float* w2 = (const float*)d_in[4];
    const float* b2 = (const float*)d_in[5];
    float* out = (float*)d_out;

    // Header (first 128 KB):
    //   [0,64)        counts (8 int)
    //   [64,128)      cursors (8 int)
    //   [256,8448)    top_e  ushort[4096]
    //   [8448,41216)  top_g  f32[8192]
    //   [41216,73984) row_tok int[8192]   ((n<<1)|k)
    //   [73984,106752) row_gate f32[8192]
    // Data: wt 32M | hbuf 32M | ybuf1 16M  => total 84,017,152 B (unchanged)
    // xb (bf16 x, 8M) ALIASES the first half of ybuf1: pack_x -> ffn1 reads it,
    // then ffn2 overwrites ybuf1 (stream-ordered, safe).
    char* ws = (char*)d_ws;
    int*            counts   = (int*)(ws + 0);
    int*            cursors  = (int*)(ws + 64);
    unsigned short* top_e    = (unsigned short*)(ws + 256);
    float*          top_g    = (float*)(ws + 8448);
    int*            row_tok  = (int*)(ws + 41216);
    float*          row_gate = (float*)(ws + 73984);

    const size_t WT_OFF    = (size_t)1 << 17;
    const size_t HBUF_OFF  = WT_OFF + (size_t)NE * DIM * HID * 2;      // +32M
    const size_t YBUF_OFF  = HBUF_OFF + (size_t)NROWS * HID * 2;       // +32M
    const size_t NEEDED    = YBUF_OFF + (size_t)N_TOK * DIM * 4;       // +16M = 84,017,152

    if (ws_size < NEEDED) {
        zero_out_kernel<<<dim3(N_TOK * DIM / 256), dim3(256), 0, stream>>>(out);
        return;
    }

    unsigned short* wt    = (unsigned short*)(ws + WT_OFF);
    unsigned short* hbuf  = (unsigned short*)(ws + HBUF_OFF);
    float*          ybuf1 = (float*)(ws + YBUF_OFF);
    unsigned short* xb    = (unsigned short*)(ws + YBUF_OFF);          // alias (see above)

    init_hdr_kernel<<<dim3(1), dim3(64), 0, stream>>>((int*)ws);
    gate_kernel<<<dim3(N_TOK / 4), dim3(256), 0, stream>>>(x, wg, counts, top_e, top_g);
    scatter_kernel<<<dim3(N_TOK / 256), dim3(256), 0, stream>>>(counts, cursors, top_e, top_g, row_tok, row_gate);
    pack_x_kernel<<<dim3(N_TOK * DIM / (256 * 8)), dim3(256), 0, stream>>>(x, xb);
    // w1 [e][D][H] -> w1T [e][H][D]
    transpose_kernel<<<dim3(DIM / 64, HID / 64, NE), dim3(256), 0, stream>>>(w1, wt, DIM, HID);
    ffn1_fast3<<<dim3(64 * NE * (HID / 128)), dim3(256), 0, stream>>>(xb, wt, b1, counts, row_tok, hbuf);
    // w2 [e][H][D] -> w2T [e][D][H]
    transpose_kernel<<<dim3(HID / 64, DIM / 64, NE), dim3(256), 0, stream>>>(w2, wt, HID, DIM);
    ffn2_fast5<<<dim3(64 * NE * (DIM / 128)), dim3(256), 0, stream>>>(hbuf, wt, b2, counts, row_tok, row_gate, out, ybuf1);
    combine_kernel<<<dim3(N_TOK * DIM / 1024), dim3(256), 0, stream>>>((float4*)out, (const float4*)ybuf1);
}

// Round 4
// 489.276 us; speedup vs baseline: 1.0965x; 1.0523x over previous
//
#include <hip/hip_runtime.h>
#include <math.h>
#include <stdint.h>

#define N_TOK 4096
#define DIM   1024
#define HID   2048
#define NE    8
#define NROWS (N_TOK * 2)   // 8192 (token, k) assignments
#define LDST  72            // transpose-kernel LDS tile stride (shorts)
#define OBST  144           // ffn1 epilogue bounce stride (shorts)
#define MAXSLOT 72          // max 128-row tiles over all experts (64 + 7 worst case, padded)

typedef __attribute__((ext_vector_type(8))) short bf16x8;
typedef __attribute__((ext_vector_type(4))) float f32x4;

__device__ __forceinline__ unsigned short f2bf(float f) {
    union { unsigned int i; float f; } v; v.f = f;
    unsigned int u = v.i;
    return (unsigned short)((u + 0x7FFFu + ((u >> 16) & 1u)) >> 16);
}
__device__ __forceinline__ int clampi(int v, int lo, int hi) {
    return v < lo ? lo : (v > hi ? hi : v);
}
__device__ __forceinline__ void cvt8(const float* p, unsigned short* o) {
    float4 a = *(const float4*)p;
    float4 b = *(const float4*)(p + 4);
    o[0] = f2bf(a.x); o[1] = f2bf(a.y); o[2] = f2bf(a.z); o[3] = f2bf(a.w);
    o[4] = f2bf(b.x); o[5] = f2bf(b.y); o[6] = f2bf(b.z); o[7] = f2bf(b.w);
}
__device__ __forceinline__ float fast_gelu(float v) {
    float c = 0.7978845608028654f * (v + 0.044715f * v * v * v);
    float t = 1.f - 2.f / (1.f + __expf(2.f * c));   // tanh(c)
    return 0.5f * v * (1.f + t);
}
// async global->LDS, 16B per lane; LDS dest = wave-uniform base + lane*16 (LINEAR — rule #21)
__device__ __forceinline__ void gload_lds16(const void* g, void* l) {
    __builtin_amdgcn_global_load_lds(
        (const __attribute__((address_space(1))) unsigned int*)g,
        (__attribute__((address_space(3))) unsigned int*)l,
        16, 0, 0);
}

// ---------------- init: zero counts + cursors ----------------
__global__ void init_hdr_kernel(int* __restrict__ hdr) {
    if (threadIdx.x < 32) hdr[threadIdx.x] = 0;
}

// ---------------- gating: one wave per token, pure fp32 ----------------
__global__ __launch_bounds__(256) void gate_kernel(
    const float* __restrict__ x, const float* __restrict__ wg,
    int* __restrict__ counts, unsigned short* __restrict__ top_e, float* __restrict__ top_g)
{
    int wave = threadIdx.x >> 6;
    int lane = threadIdx.x & 63;
    int n = blockIdx.x * 4 + wave;
    if (n >= N_TOK) return;
    float acc[NE];
#pragma unroll
    for (int e = 0; e < NE; e++) acc[e] = 0.f;
    const float* xrow = x + (size_t)n * DIM;
    for (int d = lane; d < DIM; d += 64) {
        float xv = xrow[d];
        float4 wa = *(const float4*)(wg + (size_t)d * NE);
        float4 wb = *(const float4*)(wg + (size_t)d * NE + 4);
        acc[0] += xv * wa.x; acc[1] += xv * wa.y;
        acc[2] += xv * wa.z; acc[3] += xv * wa.w;
        acc[4] += xv * wb.x; acc[5] += xv * wb.y;
        acc[6] += xv * wb.z; acc[7] += xv * wb.w;
    }
#pragma unroll
    for (int e = 0; e < NE; e++) {
        float v = acc[e];
#pragma unroll
        for (int off = 32; off > 0; off >>= 1) v += __shfl_xor(v, off, 64);
        acc[e] = v;
    }
    if (lane == 0) {
        int e0 = 0; float v0 = acc[0];
#pragma unroll
        for (int e = 1; e < NE; e++) if (acc[e] > v0) { v0 = acc[e]; e0 = e; }
        int e1 = (e0 == 0) ? 1 : 0; float v1 = acc[e1];
#pragma unroll
        for (int e = 0; e < NE; e++) if (e != e0 && acc[e] > v1) { v1 = acc[e]; e1 = e; }
        float s = expf(v1 - v0);
        float g0 = 1.f / (1.f + s);
        float g1 = s / (1.f + s);
        atomicAdd(&counts[e0], 1);
        atomicAdd(&counts[e1], 1);
        top_e[n] = (unsigned short)(e0 | (e1 << 8));
        top_g[2 * n + 0] = g0;
        top_g[2 * n + 1] = g1;
    }
}

// ---------------- scatter: per-expert row lists; row_tok = (n<<1)|k ----------------
__global__ __launch_bounds__(256) void scatter_kernel(
    const int* __restrict__ counts, int* __restrict__ cursors,
    const unsigned short* __restrict__ top_e, const float* __restrict__ top_g,
    int* __restrict__ row_tok, float* __restrict__ row_gate)
{
    int n = blockIdx.x * 256 + threadIdx.x;
    if (n >= N_TOK) return;
    int off[NE]; int a = 0;
#pragma unroll
    for (int e = 0; e < NE; e++) { off[e] = a; a += clampi(counts[e], 0, NROWS); }
    int te = top_e[n];
#pragma unroll
    for (int k = 0; k < 2; k++) {
        int e = clampi((k == 0) ? (te & 0xFF) : ((te >> 8) & 0xFF), 0, NE - 1);
        int pos = atomicAdd(&cursors[e], 1);
        int r = clampi(off[e] + pos, 0, NROWS - 1);
        row_tok[r]  = (n << 1) | k;
        row_gate[r] = top_g[2 * n + k];
    }
}

// ---------------- plan: dense tile map. map[s] = (gr0<<18)|(nvalid<<10)|e, -1 = unused ----------------
__global__ void plan_kernel(const int* __restrict__ counts, int* __restrict__ map) {
    if (threadIdx.x == 0) {
        int s = 0, base = 0;
        for (int e = 0; e < NE; e++) {
            int c = clampi(counts[e], 0, NROWS);
            for (int mb = 0; mb * 128 < c && s < MAXSLOT; mb++) {
                int nv = c - mb * 128; if (nv > 128) nv = 128;
                map[s++] = ((base + mb * 128) << 18) | (nv << 10) | e;
            }
            base += c;
        }
        for (; s < MAXSLOT; s++) map[s] = -1;
    }
}

// ---------------- pack x: fp32 [N][D] -> bf16 [N][D] (one-time cast) ----------------
__global__ __launch_bounds__(256) void pack_x_kernel(
    const float* __restrict__ x, unsigned short* __restrict__ xb)
{
    size_t i = (size_t)(blockIdx.x * 256 + threadIdx.x) * 8;
    unsigned short o[8];
    cvt8(x + i, o);
    *(uint4*)(xb + i) = *(uint4*)o;
}

// ---------------- transpose+cast: in[e][K][N] fp32 -> out[e][N][K] bf16 ----------------
__global__ __launch_bounds__(256) void transpose_kernel(
    const float* __restrict__ in, unsigned short* __restrict__ outp, int K, int N)
{
    int e  = blockIdx.z;
    int kb = blockIdx.x;
    int nb = blockIdx.y;
    __shared__ __align__(16) unsigned short tile[64 * LDST];
    int t = threadIdx.x;

    int r = t >> 2, cq = t & 3;
    const float* sp = in + ((size_t)e * K + kb * 64 + r) * N + nb * 64 + cq * 16;
    unsigned short v[16];
    cvt8(sp, v);
    cvt8(sp + 8, v + 8);
    *(uint4*)(&tile[r * LDST + cq * 16 + 0]) = *(uint4*)(v + 0);
    *(uint4*)(&tile[r * LDST + cq * 16 + 8]) = *(uint4*)(v + 8);
    __syncthreads();

    int c = t >> 2, kq = t & 3;
    unsigned short o[16];
#pragma unroll
    for (int i = 0; i < 16; i++) o[i] = tile[(kq * 16 + i) * LDST + c];
    unsigned short* dp = outp + ((size_t)e * N + nb * 64 + c) * K + kb * 64 + kq * 16;
    *(uint4*)(dp + 0) = *(uint4*)(o + 0);
    *(uint4*)(dp + 8) = *(uint4*)(o + 8);
}

// ---------------- FFN1: 128x128 tile, dbuf 2-phase, slot map, XCD swizzle, XOR-swizzled LDS ----------------
// LDS involution: slot (row, c16) holds global chunk (row, c16 ^ (row&7)); write side pre-swizzles
// the GLOBAL per-lane address (gload_lds dest stays linear), read side XORs the chunk index.
__global__ __launch_bounds__(256) void ffn1_fast4(
    const unsigned short* __restrict__ xb,    // [N][D] bf16
    const unsigned short* __restrict__ w1t,   // [e][H][D] bf16
    const float* __restrict__ b1,
    const int* __restrict__ map,
    const int* __restrict__ row_tok,
    unsigned short* __restrict__ h)
{
    // XCD swizzle: grid = MAXSLOT*16 = 1152 = 8*144; chunk of 144 logical ids per XCD
    int lid = blockIdx.x;
    int logical = (lid & 7) * (MAXSLOT * 16 / 8) + (lid >> 3);
    int nb   = logical & 15;
    int slot = logical >> 4;

    int mv = map[slot];
    if (mv < 0) return;
    int e      = mv & 0x3FF;
    int nvalid = (mv >> 10) & 0xFF;
    int gr0    = ((unsigned)mv) >> 18;

    __shared__ __align__(16) unsigned short lds[4 * 8192];   // [buf][A|B][128][64] linear
    __shared__ int ltok[128];

    int t = threadIdx.x;
    if (t < 128) {
        int rl = clampi(t, 0, nvalid - 1);
        int idx = clampi(gr0 + rl, 0, NROWS - 1);
        ltok[t] = clampi(row_tok[idx] >> 1, 0, N_TOK - 1);   // decode token
    }
    __syncthreads();

    const int n0 = nb * 128;
    int w = t >> 6;
    const unsigned short* ga[4];
    const unsigned short* gb[4];
    int lofs[4];
#pragma unroll
    for (int i = 0; i < 4; i++) {
        int idx = i * 256 + t;              // 0..1023 -> (row, 16B-chunk)
        int row = idx >> 3, cc = idx & 7;
        int ccs = cc ^ (row & 7);           // pre-swizzled global chunk
        ga[i] = xb + (size_t)ltok[row] * DIM + ccs * 8;
        gb[i] = w1t + ((size_t)e * HID + n0 + row) * DIM + ccs * 8;
        lofs[i] = i * 2048 + w * 512;       // wave-uniform linear LDS dest (shorts)
    }

    int lane = t & 63, quad = lane >> 4, ln = lane & 15;
    int wr = w >> 1, wc = w & 1;
    int xr = ln & 7;                        // read-side XOR key
    f32x4 acc[4][4];
#pragma unroll
    for (int i = 0; i < 4; i++)
#pragma unroll
        for (int j = 0; j < 4; j++) acc[i][j] = (f32x4){0.f, 0.f, 0.f, 0.f};

    // prologue: stage tile 0 into buffer 0
#pragma unroll
    for (int i = 0; i < 4; i++) {
        gload_lds16(ga[i], lds + lofs[i]);
        gload_lds16(gb[i], lds + 8192 + lofs[i]);
    }
    __syncthreads();

    int cur = 0;
    for (int kt = 0; kt < DIM / 64; kt++) {
        int nxt = cur ^ 1;
        if (kt + 1 < DIM / 64) {
            int k0 = (kt + 1) * 64;
            unsigned short* dA = lds + nxt * 16384;
            unsigned short* dB = dA + 8192;
#pragma unroll
            for (int i = 0; i < 4; i++) {
                gload_lds16(ga[i] + k0, dA + lofs[i]);
                gload_lds16(gb[i] + k0, dB + lofs[i]);
            }
        }
        const unsigned short* sA = lds + cur * 16384;
        const unsigned short* sB = sA + 8192;
#pragma unroll
        for (int kk = 0; kk < 2; kk++) {
            bf16x8 af[4], bf[4];
#pragma unroll
            for (int s = 0; s < 4; s++)
                af[s] = *(const bf16x8*)(&sA[(wr * 64 + s * 16 + ln) * 64 + (((kk * 4 + quad) ^ xr) * 8)]);
#pragma unroll
            for (int s = 0; s < 4; s++)
                bf[s] = *(const bf16x8*)(&sB[(wc * 64 + s * 16 + ln) * 64 + (((kk * 4 + quad) ^ xr) * 8)]);
#pragma unroll
            for (int i = 0; i < 4; i++)
#pragma unroll
                for (int j = 0; j < 4; j++)
                    acc[i][j] = __builtin_amdgcn_mfma_f32_16x16x32_bf16(af[i], bf[j], acc[i][j], 0, 0, 0);
        }
        __syncthreads();
        cur = nxt;
    }

    // epilogue: bounce tile through LDS, store coalesced 256B rows
    unsigned short* ob = lds;                // [128][OBST]
#pragma unroll
    for (int j = 0; j < 4; j++) {
        int colL = wc * 64 + j * 16 + ln;
        float bias = b1[e * HID + n0 + colL];
#pragma unroll
        for (int i = 0; i < 4; i++) {
#pragma unroll
            for (int r = 0; r < 4; r++) {
                int m = wr * 64 + i * 16 + quad * 4 + r;
                ob[m * OBST + colL] = f2bf(fast_gelu(acc[i][j][r] + bias));
            }
        }
    }
    __syncthreads();
#pragma unroll
    for (int it = 0; it < 8; it++) {
        int idx = it * 256 + t;              // 0..2047 -> (row, 16B-chunk)
        int m = idx >> 4, ch = idx & 15;
        if (m < nvalid)
            *(uint4*)(h + (size_t)(gr0 + m) * HID + n0 + ch * 8) = *(const uint4*)(ob + m * OBST + ch * 8);
    }
}

// ---------------- FFN2: 128x128 tile, dbuf 2-phase, slot map, XCD swizzle, XOR-swizzled LDS ----------------
__global__ __launch_bounds__(256) void ffn2_fast6(
    const unsigned short* __restrict__ h,
    const unsigned short* __restrict__ w2t,   // [e][D][H] bf16
    const float* __restrict__ b2,
    const int* __restrict__ map,
    const int* __restrict__ row_tok,
    const float* __restrict__ row_gate,
    float* __restrict__ out,                  // k=0 slot
    float* __restrict__ ybuf1)                // k=1 slot
{
    // XCD swizzle: grid = MAXSLOT*8 = 576 = 8*72
    int lid = blockIdx.x;
    int logical = (lid & 7) * (MAXSLOT * 8 / 8) + (lid >> 3);
    int nb   = logical & 7;
    int slot = logical >> 3;

    int mv = map[slot];
    if (mv < 0) return;
    int e      = mv & 0x3FF;
    int nvalid = (mv >> 10) & 0xFF;
    int gr0    = ((unsigned)mv) >> 18;

    __shared__ __align__(16) unsigned short lds[4 * 8192];   // [buf][A|B][128][64] linear
    __shared__ int   ltok2[128];              // (n<<1)|k
    __shared__ float lgate[128];

    int t = threadIdx.x;
    if (t < 128) {
        int rl = clampi(t, 0, nvalid - 1);
        int idx = clampi(gr0 + rl, 0, NROWS - 1);
        ltok2[t] = clampi(row_tok[idx], 0, 2 * N_TOK - 1);
        lgate[t] = row_gate[idx];
    }
    __syncthreads();

    const int n0 = nb * 128;
    int w = t >> 6;
    const unsigned short* ga[4];
    const unsigned short* gb[4];
    int lofs[4];
#pragma unroll
    for (int i = 0; i < 4; i++) {
        int idx = i * 256 + t;
        int row = idx >> 3, cc = idx & 7;
        int ccs = cc ^ (row & 7);           // pre-swizzled global chunk
        int arow = clampi(gr0 + row, 0, NROWS - 1);
        ga[i] = h + (size_t)arow * HID + ccs * 8;
        gb[i] = w2t + ((size_t)e * DIM + n0 + row) * HID + ccs * 8;
        lofs[i] = i * 2048 + w * 512;
    }

    int lane = t & 63, quad = lane >> 4, ln = lane & 15;
    int wr = w >> 1, wc = w & 1;
    int xr = ln & 7;
    f32x4 acc[4][4];
#pragma unroll
    for (int i = 0; i < 4; i++)
#pragma unroll
        for (int j = 0; j < 4; j++) acc[i][j] = (f32x4){0.f, 0.f, 0.f, 0.f};

    // prologue
#pragma unroll
    for (int i = 0; i < 4; i++) {
        gload_lds16(ga[i], lds + lofs[i]);
        gload_lds16(gb[i], lds + 8192 + lofs[i]);
    }
    __syncthreads();

    int cur = 0;
    for (int kt = 0; kt < HID / 64; kt++) {
        int nxt = cur ^ 1;
        if (kt + 1 < HID / 64) {
            int k0 = (kt + 1) * 64;
            unsigned short* dA = lds + nxt * 16384;
            unsigned short* dB = dA + 8192;
#pragma unroll
            for (int i = 0; i < 4; i++) {
                gload_lds16(ga[i] + k0, dA + lofs[i]);
                gload_lds16(gb[i] + k0, dB + lofs[i]);
            }
        }
        const unsigned short* sA = lds + cur * 16384;
        const unsigned short* sB = sA + 8192;
#pragma unroll
        for (int kk = 0; kk < 2; kk++) {
            bf16x8 af[4], bf[4];
#pragma unroll
            for (int s = 0; s < 4; s++)
                af[s] = *(const bf16x8*)(&sA[(wr * 64 + s * 16 + ln) * 64 + (((kk * 4 + quad) ^ xr) * 8)]);
#pragma unroll
            for (int s = 0; s < 4; s++)
                bf[s] = *(const bf16x8*)(&sB[(wc * 64 + s * 16 + ln) * 64 + (((kk * 4 + quad) ^ xr) * 8)]);
#pragma unroll
            for (int i = 0; i < 4; i++)
#pragma unroll
                for (int j = 0; j < 4; j++)
                    acc[i][j] = __builtin_amdgcn_mfma_f32_16x16x32_bf16(af[i], bf[j], acc[i][j], 0, 0, 0);
        }
        __syncthreads();
        cur = nxt;
    }

#pragma unroll
    for (int j = 0; j < 4; j++) {
        int col = n0 + wc * 64 + j * 16 + ln;
        float bias = b2[e * DIM + col];
#pragma unroll
        for (int i = 0; i < 4; i++) {
#pragma unroll
            for (int r = 0; r < 4; r++) {
                int m = wr * 64 + i * 16 + quad * 4 + r;
                if (m < nvalid) {
                    int rt  = ltok2[m];
                    int tok = rt >> 1;
                    float vv = (acc[i][j][r] + bias) * lgate[m];
                    float* dst = (rt & 1) ? ybuf1 : out;    // exactly one writer per (tok,col,k)
                    dst[(size_t)tok * DIM + col] = vv;
                }
            }
        }
    }
}

// ---------------- combine: out += ybuf1 ----------------
__global__ __launch_bounds__(256) void combine_kernel(
    float4* __restrict__ out4, const float4* __restrict__ y4)
{
    int i = blockIdx.x * 256 + threadIdx.x;   // 1M float4
    float4 a = out4[i];
    float4 b = y4[i];
    out4[i] = make_float4(a.x + b.x, a.y + b.y, a.z + b.z, a.w + b.w);
}

__global__ __launch_bounds__(256) void zero_out_kernel(float* __restrict__ out) {
    int i = blockIdx.x * 256 + threadIdx.x;
    out[i] = 0.f;
}

// ================= host =================
extern "C" void kernel_launch(void* const* d_in, const int* in_sizes, int n_in,
                              void* d_out, int out_size, void* d_ws, size_t ws_size,
                              hipStream_t stream) {
    const float* x  = (const float*)d_in[0];
    const float* wg = (const float*)d_in[1];
    const float* w1 = (const float*)d_in[2];
    const float* b1 = (const float*)d_in[3];
    const float* w2 = (const float*)d_in[4];
    const float* b2 = (const float*)d_in[5];
    float* out = (float*)d_out;

    // Header (first 128 KB):
    //   [0,64)         counts (8 int)
    //   [64,128)       cursors (8 int)
    //   [256,8448)     top_e  ushort[4096]
    //   [8448,41216)   top_g  f32[8192]
    //   [41216,73984)  row_tok int[8192]   ((n<<1)|k)
    //   [73984,106752) row_gate f32[8192]
    //   [106752,107040) map int[72]        ((gr0<<18)|(nvalid<<10)|e)
    // Data: wt 32M | hbuf 32M | ybuf1 16M  => total 84,017,152 B (unchanged)
    // xb (bf16 x, 8M) ALIASES the first half of ybuf1 (stream-ordered, safe).
    char* ws = (char*)d_ws;
    int*            counts   = (int*)(ws + 0);
    int*            cursors  = (int*)(ws + 64);
    unsigned short* top_e    = (unsigned short*)(ws + 256);
    float*          top_g    = (float*)(ws + 8448);
    int*            row_tok  = (int*)(ws + 41216);
    float*          row_gate = (float*)(ws + 73984);
    int*            map      = (int*)(ws + 106752);

    const size_t WT_OFF    = (size_t)1 << 17;
    const size_t HBUF_OFF  = WT_OFF + (size_t)NE * DIM * HID * 2;      // +32M
    const size_t YBUF_OFF  = HBUF_OFF + (size_t)NROWS * HID * 2;       // +32M
    const size_t NEEDED    = YBUF_OFF + (size_t)N_TOK * DIM * 4;       // +16M = 84,017,152

    if (ws_size < NEEDED) {
        zero_out_kernel<<<dim3(N_TOK * DIM / 256), dim3(256), 0, stream>>>(out);
        return;
    }

    unsigned short* wt    = (unsigned short*)(ws + WT_OFF);
    unsigned short* hbuf  = (unsigned short*)(ws + HBUF_OFF);
    float*          ybuf1 = (float*)(ws + YBUF_OFF);
    unsigned short* xb    = (unsigned short*)(ws + YBUF_OFF);          // alias (see above)

    init_hdr_kernel<<<dim3(1), dim3(64), 0, stream>>>((int*)ws);
    gate_kernel<<<dim3(N_TOK / 4), dim3(256), 0, stream>>>(x, wg, counts, top_e, top_g);
    scatter_kernel<<<dim3(N_TOK / 256), dim3(256), 0, stream>>>(counts, cursors, top_e, top_g, row_tok, row_gate);
    plan_kernel<<<dim3(1), dim3(64), 0, stream>>>(counts, map);
    pack_x_kernel<<<dim3(N_TOK * DIM / (256 * 8)), dim3(256), 0, stream>>>(x, xb);
    // w1 [e][D][H] -> w1T [e][H][D]
    transpose_kernel<<<dim3(DIM / 64, HID / 64, NE), dim3(256), 0, stream>>>(w1, wt, DIM, HID);
    ffn1_fast4<<<dim3(MAXSLOT * 16), dim3(256), 0, stream>>>(xb, wt, b1, map, row_tok, hbuf);
    // w2 [e][H][D] -> w2T [e][D][H]
    transpose_kernel<<<dim3(HID / 64, DIM / 64, NE), dim3(256), 0, stream>>>(w2, wt, HID, DIM);
    ffn2_fast6<<<dim3(MAXSLOT * 8), dim3(256), 0, stream>>>(hbuf, wt, b2, map, row_tok, row_gate, out, ybuf1);
    combine_kernel<<<dim3(N_TOK * DIM / 1024), dim3(256), 0, stream>>>((float4*)out, (const float4*)ybuf1);
}

// Round 5
// 373.388 us; speedup vs baseline: 1.4368x; 1.3104x over previous
//
#include <hip/hip_runtime.h>
#include <math.h>
#include <stdint.h>

#define N_TOK 4096
#define DIM   1024
#define HID   2048
#define NE    8
#define NROWS (N_TOK * 2)   // 8192 (token, k) assignments
#define LDST  72            // transpose-kernel LDS tile stride (shorts)
#define OBST  144           // ffn1 epilogue bounce stride (shorts)
#define MAXSLOT 72          // max 128-row tiles over all experts (64 + 7 worst case, padded)
#define TPT   16            // tokens per thread in scatter_plan (N_TOK/256)

typedef __attribute__((ext_vector_type(8))) short bf16x8;
typedef __attribute__((ext_vector_type(4))) float f32x4;

__device__ __forceinline__ unsigned short f2bf(float f) {
    union { unsigned int i; float f; } v; v.f = f;
    unsigned int u = v.i;
    return (unsigned short)((u + 0x7FFFu + ((u >> 16) & 1u)) >> 16);
}
__device__ __forceinline__ int clampi(int v, int lo, int hi) {
    return v < lo ? lo : (v > hi ? hi : v);
}
__device__ __forceinline__ void cvt8(const float* p, unsigned short* o) {
    float4 a = *(const float4*)p;
    float4 b = *(const float4*)(p + 4);
    o[0] = f2bf(a.x); o[1] = f2bf(a.y); o[2] = f2bf(a.z); o[3] = f2bf(a.w);
    o[4] = f2bf(b.x); o[5] = f2bf(b.y); o[6] = f2bf(b.z); o[7] = f2bf(b.w);
}
__device__ __forceinline__ float fast_gelu(float v) {
    float c = 0.7978845608028654f * (v + 0.044715f * v * v * v);
    float t = 1.f - 2.f / (1.f + __expf(2.f * c));   // tanh(c)
    return 0.5f * v * (1.f + t);
}
// async global->LDS, 16B per lane; LDS dest = wave-uniform base + lane*16 (LINEAR — rule #21)
__device__ __forceinline__ void gload_lds16(const void* g, void* l) {
    __builtin_amdgcn_global_load_lds(
        (const __attribute__((address_space(1))) unsigned int*)g,
        (__attribute__((address_space(3))) unsigned int*)l,
        16, 0, 0);
}

// ---------------- gating: one wave per token, pure fp32, NO ATOMICS ----------------
__global__ __launch_bounds__(256) void gate_kernel(
    const float* __restrict__ x, const float* __restrict__ wg,
    unsigned short* __restrict__ top_e, float* __restrict__ top_g)
{
    int wave = threadIdx.x >> 6;
    int lane = threadIdx.x & 63;
    int n = blockIdx.x * 4 + wave;
    if (n >= N_TOK) return;
    float acc[NE];
#pragma unroll
    for (int e = 0; e < NE; e++) acc[e] = 0.f;
    const float* xrow = x + (size_t)n * DIM;
    for (int d = lane; d < DIM; d += 64) {
        float xv = xrow[d];
        float4 wa = *(const float4*)(wg + (size_t)d * NE);
        float4 wb = *(const float4*)(wg + (size_t)d * NE + 4);
        acc[0] += xv * wa.x; acc[1] += xv * wa.y;
        acc[2] += xv * wa.z; acc[3] += xv * wa.w;
        acc[4] += xv * wb.x; acc[5] += xv * wb.y;
        acc[6] += xv * wb.z; acc[7] += xv * wb.w;
    }
#pragma unroll
    for (int e = 0; e < NE; e++) {
        float v = acc[e];
#pragma unroll
        for (int off = 32; off > 0; off >>= 1) v += __shfl_xor(v, off, 64);
        acc[e] = v;
    }
    if (lane == 0) {
        int e0 = 0; float v0 = acc[0];
#pragma unroll
        for (int e = 1; e < NE; e++) if (acc[e] > v0) { v0 = acc[e]; e0 = e; }
        int e1 = (e0 == 0) ? 1 : 0; float v1 = acc[e1];
#pragma unroll
        for (int e = 0; e < NE; e++) if (e != e0 && acc[e] > v1) { v1 = acc[e]; e1 = e; }
        float s = expf(v1 - v0);
        float g0 = 1.f / (1.f + s);
        float g1 = s / (1.f + s);
        top_e[n] = (unsigned short)(e0 | (e1 << 8));
        top_g[2 * n + 0] = g0;
        top_g[2 * n + 1] = g1;
    }
}

// ---------------- scatter+plan: ONE workgroup, zero atomics ----------------
// Pass 1: per-thread expert histogram packed in uint64 (8 bits/expert, max 16 each).
// Scan:   per-expert exclusive prefix over threads (LDS), totals -> expert bases + map.
// Pass 2: each thread writes its tokens' rows at deterministic positions.
__global__ __launch_bounds__(256) void scatter_plan_kernel(
    const unsigned short* __restrict__ top_e, const float* __restrict__ top_g,
    int* __restrict__ row_tok, float* __restrict__ row_gate, int* __restrict__ map)
{
    __shared__ int lpre[256][NE];   // counts, then exclusive prefix, then running cursor
    __shared__ int etot[NE];
    __shared__ int ebase[NE];
    int t = threadIdx.x;

    unsigned long long c64 = 0ull;
    unsigned short te[TPT];
#pragma unroll
    for (int i = 0; i < TPT; i++) {
        int v = top_e[t * TPT + i];
        te[i] = (unsigned short)v;
        c64 += 1ull << ((v & 7) * 8);
        c64 += 1ull << (((v >> 8) & 7) * 8);
    }
#pragma unroll
    for (int e = 0; e < NE; e++) lpre[t][e] = (int)((c64 >> (e * 8)) & 0xFF);
    __syncthreads();

    if (t < NE) {                    // one thread per expert: scan 256 entries
        int s = 0;
        for (int i = 0; i < 256; i++) { int c = lpre[i][t]; lpre[i][t] = s; s += c; }
        etot[t] = s;
    }
    __syncthreads();
    if (t == 0) {
        int b = 0;
#pragma unroll
        for (int e = 0; e < NE; e++) { ebase[e] = b; b += etot[e]; }
        int s = 0; b = 0;
        for (int e = 0; e < NE; e++) {
            int c = clampi(etot[e], 0, NROWS);
            for (int mb = 0; mb * 128 < c && s < MAXSLOT; mb++) {
                int nv = c - mb * 128; if (nv > 128) nv = 128;
                map[s++] = ((b + mb * 128) << 18) | (nv << 10) | e;
            }
            b += c;
        }
        for (; s < MAXSLOT; s++) map[s] = -1;
    }
    __syncthreads();

#pragma unroll
    for (int i = 0; i < TPT; i++) {
        int n = t * TPT + i;
        int v = te[i];
#pragma unroll
        for (int k = 0; k < 2; k++) {
            int e = (k ? (v >> 8) : v) & 7;
            int r = clampi(ebase[e] + lpre[t][e]++, 0, NROWS - 1);
            row_tok[r]  = (n << 1) | k;
            row_gate[r] = top_g[2 * n + k];
        }
    }
}

// ---------------- pack x: fp32 [N][D] -> bf16 [N][D] (one-time cast) ----------------
__global__ __launch_bounds__(256) void pack_x_kernel(
    const float* __restrict__ x, unsigned short* __restrict__ xb)
{
    size_t i = (size_t)(blockIdx.x * 256 + threadIdx.x) * 8;
    unsigned short o[8];
    cvt8(x + i, o);
    *(uint4*)(xb + i) = *(uint4*)o;
}

// ---------------- transpose+cast: in[e][K][N] fp32 -> out[e][N][K] bf16 ----------------
__global__ __launch_bounds__(256) void transpose_kernel(
    const float* __restrict__ in, unsigned short* __restrict__ outp, int K, int N)
{
    int e  = blockIdx.z;
    int kb = blockIdx.x;
    int nb = blockIdx.y;
    __shared__ __align__(16) unsigned short tile[64 * LDST];
    int t = threadIdx.x;

    int r = t >> 2, cq = t & 3;
    const float* sp = in + ((size_t)e * K + kb * 64 + r) * N + nb * 64 + cq * 16;
    unsigned short v[16];
    cvt8(sp, v);
    cvt8(sp + 8, v + 8);
    *(uint4*)(&tile[r * LDST + cq * 16 + 0]) = *(uint4*)(v + 0);
    *(uint4*)(&tile[r * LDST + cq * 16 + 8]) = *(uint4*)(v + 8);
    __syncthreads();

    int c = t >> 2, kq = t & 3;
    unsigned short o[16];
#pragma unroll
    for (int i = 0; i < 16; i++) o[i] = tile[(kq * 16 + i) * LDST + c];
    unsigned short* dp = outp + ((size_t)e * N + nb * 64 + c) * K + kb * 64 + kq * 16;
    *(uint4*)(dp + 0) = *(uint4*)(o + 0);
    *(uint4*)(dp + 8) = *(uint4*)(o + 8);
}

// ---------------- FFN1: 128x128 tile, dbuf 2-phase, slot map, XCD swizzle, XOR-swizzled LDS ----------------
// LDS involution: slot (row, c16) holds global chunk (row, c16 ^ (row&7)); write side pre-swizzles
// the GLOBAL per-lane address (gload_lds dest stays linear), read side XORs the chunk index.
__global__ __launch_bounds__(256) void ffn1_fast4(
    const unsigned short* __restrict__ xb,    // [N][D] bf16
    const unsigned short* __restrict__ w1t,   // [e][H][D] bf16
    const float* __restrict__ b1,
    const int* __restrict__ map,
    const int* __restrict__ row_tok,
    unsigned short* __restrict__ h)
{
    // XCD swizzle: grid = MAXSLOT*16 = 1152 = 8*144; chunk of 144 logical ids per XCD
    int lid = blockIdx.x;
    int logical = (lid & 7) * (MAXSLOT * 16 / 8) + (lid >> 3);
    int nb   = logical & 15;
    int slot = logical >> 4;

    int mv = map[slot];
    if (mv < 0) return;
    int e      = mv & 0x3FF;
    int nvalid = (mv >> 10) & 0xFF;
    int gr0    = ((unsigned)mv) >> 18;

    __shared__ __align__(16) unsigned short lds[4 * 8192];   // [buf][A|B][128][64] linear
    __shared__ int ltok[128];

    int t = threadIdx.x;
    if (t < 128) {
        int rl = clampi(t, 0, nvalid - 1);
        int idx = clampi(gr0 + rl, 0, NROWS - 1);
        ltok[t] = clampi(row_tok[idx] >> 1, 0, N_TOK - 1);   // decode token
    }
    __syncthreads();

    const int n0 = nb * 128;
    int w = t >> 6;
    const unsigned short* ga[4];
    const unsigned short* gb[4];
    int lofs[4];
#pragma unroll
    for (int i = 0; i < 4; i++) {
        int idx = i * 256 + t;              // 0..1023 -> (row, 16B-chunk)
        int row = idx >> 3, cc = idx & 7;
        int ccs = cc ^ (row & 7);           // pre-swizzled global chunk
        ga[i] = xb + (size_t)ltok[row] * DIM + ccs * 8;
        gb[i] = w1t + ((size_t)e * HID + n0 + row) * DIM + ccs * 8;
        lofs[i] = i * 2048 + w * 512;       // wave-uniform linear LDS dest (shorts)
    }

    int lane = t & 63, quad = lane >> 4, ln = lane & 15;
    int wr = w >> 1, wc = w & 1;
    int xr = ln & 7;                        // read-side XOR key
    f32x4 acc[4][4];
#pragma unroll
    for (int i = 0; i < 4; i++)
#pragma unroll
        for (int j = 0; j < 4; j++) acc[i][j] = (f32x4){0.f, 0.f, 0.f, 0.f};

    // prologue: stage tile 0 into buffer 0
#pragma unroll
    for (int i = 0; i < 4; i++) {
        gload_lds16(ga[i], lds + lofs[i]);
        gload_lds16(gb[i], lds + 8192 + lofs[i]);
    }
    __syncthreads();

    int cur = 0;
    for (int kt = 0; kt < DIM / 64; kt++) {
        int nxt = cur ^ 1;
        if (kt + 1 < DIM / 64) {
            int k0 = (kt + 1) * 64;
            unsigned short* dA = lds + nxt * 16384;
            unsigned short* dB = dA + 8192;
#pragma unroll
            for (int i = 0; i < 4; i++) {
                gload_lds16(ga[i] + k0, dA + lofs[i]);
                gload_lds16(gb[i] + k0, dB + lofs[i]);
            }
        }
        const unsigned short* sA = lds + cur * 16384;
        const unsigned short* sB = sA + 8192;
#pragma unroll
        for (int kk = 0; kk < 2; kk++) {
            bf16x8 af[4], bf[4];
#pragma unroll
            for (int s = 0; s < 4; s++)
                af[s] = *(const bf16x8*)(&sA[(wr * 64 + s * 16 + ln) * 64 + (((kk * 4 + quad) ^ xr) * 8)]);
#pragma unroll
            for (int s = 0; s < 4; s++)
                bf[s] = *(const bf16x8*)(&sB[(wc * 64 + s * 16 + ln) * 64 + (((kk * 4 + quad) ^ xr) * 8)]);
#pragma unroll
            for (int i = 0; i < 4; i++)
#pragma unroll
                for (int j = 0; j < 4; j++)
                    acc[i][j] = __builtin_amdgcn_mfma_f32_16x16x32_bf16(af[i], bf[j], acc[i][j], 0, 0, 0);
        }
        __syncthreads();
        cur = nxt;
    }

    // epilogue: bounce tile through LDS, store coalesced 256B rows
    unsigned short* ob = lds;                // [128][OBST]
#pragma unroll
    for (int j = 0; j < 4; j++) {
        int colL = wc * 64 + j * 16 + ln;
        float bias = b1[e * HID + n0 + colL];
#pragma unroll
        for (int i = 0; i < 4; i++) {
#pragma unroll
            for (int r = 0; r < 4; r++) {
                int m = wr * 64 + i * 16 + quad * 4 + r;
                ob[m * OBST + colL] = f2bf(fast_gelu(acc[i][j][r] + bias));
            }
        }
    }
    __syncthreads();
#pragma unroll
    for (int it = 0; it < 8; it++) {
        int idx = it * 256 + t;              // 0..2047 -> (row, 16B-chunk)
        int m = idx >> 4, ch = idx & 15;
        if (m < nvalid)
            *(uint4*)(h + (size_t)(gr0 + m) * HID + n0 + ch * 8) = *(const uint4*)(ob + m * OBST + ch * 8);
    }
}

// ---------------- FFN2: 128x128 tile, dbuf 2-phase, slot map, XCD swizzle, XOR-swizzled LDS ----------------
__global__ __launch_bounds__(256) void ffn2_fast6(
    const unsigned short* __restrict__ h,
    const unsigned short* __restrict__ w2t,   // [e][D][H] bf16
    const float* __restrict__ b2,
    const int* __restrict__ map,
    const int* __restrict__ row_tok,
    const float* __restrict__ row_gate,
    float* __restrict__ out,                  // k=0 slot
    float* __restrict__ ybuf1)                // k=1 slot
{
    // XCD swizzle: grid = MAXSLOT*8 = 576 = 8*72
    int lid = blockIdx.x;
    int logical = (lid & 7) * (MAXSLOT * 8 / 8) + (lid >> 3);
    int nb   = logical & 7;
    int slot = logical >> 3;

    int mv = map[slot];
    if (mv < 0) return;
    int e      = mv & 0x3FF;
    int nvalid = (mv >> 10) & 0xFF;
    int gr0    = ((unsigned)mv) >> 18;

    __shared__ __align__(16) unsigned short lds[4 * 8192];   // [buf][A|B][128][64] linear
    __shared__ int   ltok2[128];              // (n<<1)|k
    __shared__ float lgate[128];

    int t = threadIdx.x;
    if (t < 128) {
        int rl = clampi(t, 0, nvalid - 1);
        int idx = clampi(gr0 + rl, 0, NROWS - 1);
        ltok2[t] = clampi(row_tok[idx], 0, 2 * N_TOK - 1);
        lgate[t] = row_gate[idx];
    }
    __syncthreads();

    const int n0 = nb * 128;
    int w = t >> 6;
    const unsigned short* ga[4];
    const unsigned short* gb[4];
    int lofs[4];
#pragma unroll
    for (int i = 0; i < 4; i++) {
        int idx = i * 256 + t;
        int row = idx >> 3, cc = idx & 7;
        int ccs = cc ^ (row & 7);           // pre-swizzled global chunk
        int arow = clampi(gr0 + row, 0, NROWS - 1);
        ga[i] = h + (size_t)arow * HID + ccs * 8;
        gb[i] = w2t + ((size_t)e * DIM + n0 + row) * HID + ccs * 8;
        lofs[i] = i * 2048 + w * 512;
    }

    int lane = t & 63, quad = lane >> 4, ln = lane & 15;
    int wr = w >> 1, wc = w & 1;
    int xr = ln & 7;
    f32x4 acc[4][4];
#pragma unroll
    for (int i = 0; i < 4; i++)
#pragma unroll
        for (int j = 0; j < 4; j++) acc[i][j] = (f32x4){0.f, 0.f, 0.f, 0.f};

    // prologue
#pragma unroll
    for (int i = 0; i < 4; i++) {
        gload_lds16(ga[i], lds + lofs[i]);
        gload_lds16(gb[i], lds + 8192 + lofs[i]);
    }
    __syncthreads();

    int cur = 0;
    for (int kt = 0; kt < HID / 64; kt++) {
        int nxt = cur ^ 1;
        if (kt + 1 < HID / 64) {
            int k0 = (kt + 1) * 64;
            unsigned short* dA = lds + nxt * 16384;
            unsigned short* dB = dA + 8192;
#pragma unroll
            for (int i = 0; i < 4; i++) {
                gload_lds16(ga[i] + k0, dA + lofs[i]);
                gload_lds16(gb[i] + k0, dB + lofs[i]);
            }
        }
        const unsigned short* sA = lds + cur * 16384;
        const unsigned short* sB = sA + 8192;
#pragma unroll
        for (int kk = 0; kk < 2; kk++) {
            bf16x8 af[4], bf[4];
#pragma unroll
            for (int s = 0; s < 4; s++)
                af[s] = *(const bf16x8*)(&sA[(wr * 64 + s * 16 + ln) * 64 + (((kk * 4 + quad) ^ xr) * 8)]);
#pragma unroll
            for (int s = 0; s < 4; s++)
                bf[s] = *(const bf16x8*)(&sB[(wc * 64 + s * 16 + ln) * 64 + (((kk * 4 + quad) ^ xr) * 8)]);
#pragma unroll
            for (int i = 0; i < 4; i++)
#pragma unroll
                for (int j = 0; j < 4; j++)
                    acc[i][j] = __builtin_amdgcn_mfma_f32_16x16x32_bf16(af[i], bf[j], acc[i][j], 0, 0, 0);
        }
        __syncthreads();
        cur = nxt;
    }

#pragma unroll
    for (int j = 0; j < 4; j++) {
        int col = n0 + wc * 64 + j * 16 + ln;
        float bias = b2[e * DIM + col];
#pragma unroll
        for (int i = 0; i < 4; i++) {
#pragma unroll
            for (int r = 0; r < 4; r++) {
                int m = wr * 64 + i * 16 + quad * 4 + r;
                if (m < nvalid) {
                    int rt  = ltok2[m];
                    int tok = rt >> 1;
                    float vv = (acc[i][j][r] + bias) * lgate[m];
                    float* dst = (rt & 1) ? ybuf1 : out;    // exactly one writer per (tok,col,k)
                    dst[(size_t)tok * DIM + col] = vv;
                }
            }
        }
    }
}

// ---------------- combine: out += ybuf1 ----------------
__global__ __launch_bounds__(256) void combine_kernel(
    float4* __restrict__ out4, const float4* __restrict__ y4)
{
    int i = blockIdx.x * 256 + threadIdx.x;   // 1M float4
    float4 a = out4[i];
    float4 b = y4[i];
    out4[i] = make_float4(a.x + b.x, a.y + b.y, a.z + b.z, a.w + b.w);
}

__global__ __launch_bounds__(256) void zero_out_kernel(float* __restrict__ out) {
    int i = blockIdx.x * 256 + threadIdx.x;
    out[i] = 0.f;
}

// ================= host =================
extern "C" void kernel_launch(void* const* d_in, const int* in_sizes, int n_in,
                              void* d_out, int out_size, void* d_ws, size_t ws_size,
                              hipStream_t stream) {
    const float* x  = (const float*)d_in[0];
    const float* wg = (const float*)d_in[1];
    const float* w1 = (const float*)d_in[2];
    const float* b1 = (const float*)d_in[3];
    const float* w2 = (const float*)d_in[4];
    const float* b2 = (const float*)d_in[5];
    float* out = (float*)d_out;

    // Header (first 128 KB):
    //   [256,8448)     top_e  ushort[4096]
    //   [8448,41216)   top_g  f32[8192]
    //   [41216,73984)  row_tok int[8192]   ((n<<1)|k)
    //   [73984,106752) row_gate f32[8192]
    //   [106752,107040) map int[72]        ((gr0<<18)|(nvalid<<10)|e)
    // Data: wt 32M | hbuf 32M | ybuf1 16M  => total 84,017,152 B (unchanged)
    // xb (bf16 x, 8M) ALIASES the first half of ybuf1 (stream-ordered, safe).
    char* ws = (char*)d_ws;
    unsigned short* top_e    = (unsigned short*)(ws + 256);
    float*          top_g    = (float*)(ws + 8448);
    int*            row_tok  = (int*)(ws + 41216);
    float*          row_gate = (float*)(ws + 73984);
    int*            map      = (int*)(ws + 106752);

    const size_t WT_OFF    = (size_t)1 << 17;
    const size_t HBUF_OFF  = WT_OFF + (size_t)NE * DIM * HID * 2;      // +32M
    const size_t YBUF_OFF  = HBUF_OFF + (size_t)NROWS * HID * 2;       // +32M
    const size_t NEEDED    = YBUF_OFF + (size_t)N_TOK * DIM * 4;       // +16M = 84,017,152

    if (ws_size < NEEDED) {
        zero_out_kernel<<<dim3(N_TOK * DIM / 256), dim3(256), 0, stream>>>(out);
        return;
    }

    unsigned short* wt    = (unsigned short*)(ws + WT_OFF);
    unsigned short* hbuf  = (unsigned short*)(ws + HBUF_OFF);
    float*          ybuf1 = (float*)(ws + YBUF_OFF);
    unsigned short* xb    = (unsigned short*)(ws + YBUF_OFF);          // alias (see above)

    gate_kernel<<<dim3(N_TOK / 4), dim3(256), 0, stream>>>(x, wg, top_e, top_g);
    scatter_plan_kernel<<<dim3(1), dim3(256), 0, stream>>>(top_e, top_g, row_tok, row_gate, map);
    pack_x_kernel<<<dim3(N_TOK * DIM / (256 * 8)), dim3(256), 0, stream>>>(x, xb);
    // w1 [e][D][H] -> w1T [e][H][D]
    transpose_kernel<<<dim3(DIM / 64, HID / 64, NE), dim3(256), 0, stream>>>(w1, wt, DIM, HID);
    ffn1_fast4<<<dim3(MAXSLOT * 16), dim3(256), 0, stream>>>(xb, wt, b1, map, row_tok, hbuf);
    // w2 [e][H][D] -> w2T [e][D][H]
    transpose_kernel<<<dim3(HID / 64, DIM / 64, NE), dim3(256), 0, stream>>>(w2, wt, HID, DIM);
    ffn2_fast6<<<dim3(MAXSLOT * 8), dim3(256), 0, stream>>>(hbuf, wt, b2, map, row_tok, row_gate, out, ybuf1);
    combine_kernel<<<dim3(N_TOK * DIM / 1024), dim3(256), 0, stream>>>((float4*)out, (const float4*)ybuf1);
}